// Round 22
// baseline (32.909 us; speedup 1.0000x reference)
//
#include <hip/hip_runtime.h>
#include <hip/hip_fp16.h>

#define NUM_F  39
#define NUM_P  741      // 39*38/2
#define NPAD   768      // 48 tiles * 16
#define NPP    (NPAD + 8)   // padded lg-plane stride (3104 B: +8 banks per lg)
#define DIM    64
#define ESTRH  72       // fp16 row stride in halves; 144 B rows (16B aligned)
#define NRP    2        // row-pairs per block (4 batch rows)
#define NITEMS (2 * NUM_F * 8)   // 624 gather items per row-pair

typedef float    f32x4 __attribute__((ext_vector_type(4)));
typedef _Float16 f16x8 __attribute__((ext_vector_type(8)));
typedef _Float16 f16x2 __attribute__((ext_vector_type(2)));
typedef __fp16   h16x2 __attribute__((ext_vector_type(2)));

static __device__ __forceinline__ f16x8 pack8(float4 v0, float4 v1, float fv) {
    f16x8 hv;
    hv[0] = (_Float16)(v0.x * fv);
    hv[1] = (_Float16)(v0.y * fv);
    hv[2] = (_Float16)(v0.z * fv);
    hv[3] = (_Float16)(v0.w * fv);
    hv[4] = (_Float16)(v1.x * fv);
    hv[5] = (_Float16)(v1.y * fv);
    hv[6] = (_Float16)(v1.z * fv);
    hv[7] = (_Float16)(v1.w * fv);
    return hv;
}

static __device__ __forceinline__ f16x2 pk2(float a, float b) {
    union { h16x2 p; f16x2 v; } u;
    u.p = __builtin_amdgcn_cvt_pkrtz(a, b);
    return u.v;
}
static __device__ __forceinline__ f16x2 relu2(f16x2 x) {
#if __has_builtin(__builtin_elementwise_max)
    const f16x2 z = {(_Float16)0.f, (_Float16)0.f};
    return __builtin_elementwise_max(x, z);
#else
    f16x2 r;
    r[0] = (x[0] > (_Float16)0.f) ? x[0] : (_Float16)0.f;
    r[1] = (x[1] > (_Float16)0.f) ? x[1] : (_Float16)0.f;
    return r;
#endif
}

__global__ __launch_bounds__(512, 2) void afm_epf(
    const int*   __restrict__ feat_index,   // [B, F]
    const float* __restrict__ feat_value,   // [B, F]
    const float* __restrict__ fo_w,         // [NUM_FEATS, 1]
    const float* __restrict__ emb_table,    // [NUM_FEATS, 64]
    const float* __restrict__ att_W,        // [64, 64] (d, a)
    const float* __restrict__ att_b,        // [64]
    const float* __restrict__ att_h,        // [64]
    const float* __restrict__ p_vec,        // [64]
    const float* __restrict__ bias,         // [1]
    float*       __restrict__ out)          // [B]
{
    const int blk  = blockIdx.x;            // batch rows 4*blk .. 4*blk+3
    const int t    = threadIdx.x;
    const int wave = t >> 6;                // 0..7
    const int lane = t & 63;
    const int row  = wave >> 2;             // 0 or 1 (within row-pair)
    const int wv   = wave & 3;              // wave-within-row
    const int la   = lane & 15;             // pair-within-tile (B/C col)
    const int lg   = lane >> 4;             // k-group / C row-group

    __shared__ __half       e_lds[2][2][NUM_F][ESTRH]; // [buf][row] (22.5 KB)
    __shared__ __half       Wt[DIM][ESTRH];            // W^T fp16 (9 KB)
    __shared__ float        tsp[2][4][NPP];            // per-lg ts partials (24.8 KB, padded)
    __shared__ float        q_s[2][NPAD];              // q per pair (6.1 KB)
    __shared__ float        b_lds[DIM], h_lds[DIM], pv_lds[DIM];
    __shared__ unsigned int pairOff[NPAD];             // r*144 | (c*144<<16)
    __shared__ int          s_idx[2 * NRP * NUM_F];
    __shared__ float        s_fv[2 * NRP * NUM_F];
    __shared__ float        yf_s[2 * NRP * NUM_F];
    __shared__ float        s_yfirst[2 * NRP];
    __shared__ float        wredM[8], wredS[8], wredQ[8];

    const float4* emb4 = (const float4*)emb_table;

    // ---------------- A1: idx/fv/yf for all 4 rows + W + tables ----------------
    if (t < 2 * NRP * NUM_F) {
        int   idx = feat_index[blk * 2 * NRP * NUM_F + t];
        float fv  = feat_value[blk * 2 * NRP * NUM_F + t];
        s_idx[t]  = idx;
        s_fv[t]   = fv;
        yf_s[t]   = fo_w[idx] * fv;
    }
    if (t < DIM) {
        b_lds[t]  = att_b[t];
        h_lds[t]  = att_h[t];
        pv_lds[t] = p_vec[t];
    }
    if (t >= 192 && t < 192 + NUM_F) {   // pair table
        int r = t - 192, off = r * (2 * NUM_F - r - 1) / 2;
        const unsigned int rb = (unsigned int)(r * (ESTRH * 2));
        for (int c = r + 1; c < NUM_F; ++c) {
            pairOff[off] = rb | ((unsigned int)(c * (ESTRH * 2)) << 16);
            ++off;
        }
    }
    if (t >= 256 && t < 256 + (NPAD - NUM_P)) pairOff[NUM_P + (t - 256)] = 0;
    for (int q = t; q < DIM * DIM; q += 512) {       // W^T -> fp16 LDS
        int d = q >> 6, a = q & 63;
        Wt[a][d] = (__half)(_Float16)att_W[q];
    }
    __syncthreads();

    // y_first: waves 0..3 each reduce one of the 4 rows
    if (wave < 2 * NRP) {
        float yf = (lane < NUM_F) ? yf_s[wave * NUM_F + lane] : 0.f;
        #pragma unroll
        for (int m = 1; m < 64; m <<= 1) yf += __shfl_xor(yf, m);
        if (lane == 0) s_yfirst[wave] = yf;
    }

    // ---------------- A2: stage E for rp=0 (serial, once) ----------------
    {
        const int f0 = t >> 3, d80 = t & 7;          // item t (always < 624)
        float4 v0a = emb4[(size_t)s_idx[f0] * 16 + d80 * 2];
        float4 v0b = emb4[(size_t)s_idx[f0] * 16 + d80 * 2 + 1];
        const int  i1   = t + 512;
        const bool has1 = i1 < NITEMS;
        const int  f1 = i1 >> 3, d81 = i1 & 7;
        float4 v1a, v1b;
        if (has1) {
            v1a = emb4[(size_t)s_idx[f1] * 16 + d81 * 2];
            v1b = emb4[(size_t)s_idx[f1] * 16 + d81 * 2 + 1];
        }
        {
            int rr = (f0 >= NUM_F), ff = f0 - rr * NUM_F;
            *(f16x8*)&e_lds[0][rr][ff][d80 * 8] = pack8(v0a, v0b, s_fv[f0]);
        }
        if (has1) {
            int rr = (f1 >= NUM_F), ff = f1 - rr * NUM_F;
            *(f16x8*)&e_lds[0][rr][ff][d81 * 8] = pack8(v1a, v1b, s_fv[f1]);
        }
    }
    __syncthreads();

    // ---------------- stationary fragments (named SSA, hoisted) ----------------
    const f16x8 WA00 = *(const f16x8*)&Wt[ 0 + la][ 0 + lg * 8];
    const f16x8 WA01 = *(const f16x8*)&Wt[ 0 + la][32 + lg * 8];
    const f16x8 WA10 = *(const f16x8*)&Wt[16 + la][ 0 + lg * 8];
    const f16x8 WA11 = *(const f16x8*)&Wt[16 + la][32 + lg * 8];
    const f16x8 WA20 = *(const f16x8*)&Wt[32 + la][ 0 + lg * 8];
    const f16x8 WA21 = *(const f16x8*)&Wt[32 + la][32 + lg * 8];
    const f16x8 WA30 = *(const f16x8*)&Wt[48 + la][ 0 + lg * 8];
    const f16x8 WA31 = *(const f16x8*)&Wt[48 + la][32 + lg * 8];

    f16x8 PA0 = (f16x8)(_Float16)0.f;
    f16x8 PA1 = (f16x8)(_Float16)0.f;
    if (la == 0) {
        #pragma unroll
        for (int j = 0; j < 8; ++j) {
            PA0[j] = (_Float16)pv_lds[     lg * 8 + j];
            PA1[j] = (_Float16)pv_lds[32 + lg * 8 + j];
        }
    }

    const f32x4 b40 = *(const f32x4*)&b_lds[ 0 + lg * 4];
    const f32x4 b41 = *(const f32x4*)&b_lds[16 + lg * 4];
    const f32x4 b42 = *(const f32x4*)&b_lds[32 + lg * 4];
    const f32x4 b43 = *(const f32x4*)&b_lds[48 + lg * 4];
    // h as packed f16 pairs for the packed epilogue
    const f16x2 h20 = pk2(h_lds[ 0 + lg * 4], h_lds[ 0 + lg * 4 + 1]);
    const f16x2 h21 = pk2(h_lds[ 0 + lg * 4 + 2], h_lds[ 0 + lg * 4 + 3]);
    const f16x2 h22 = pk2(h_lds[16 + lg * 4], h_lds[16 + lg * 4 + 1]);
    const f16x2 h23 = pk2(h_lds[16 + lg * 4 + 2], h_lds[16 + lg * 4 + 3]);
    const f16x2 h24 = pk2(h_lds[32 + lg * 4], h_lds[32 + lg * 4 + 1]);
    const f16x2 h25 = pk2(h_lds[32 + lg * 4 + 2], h_lds[32 + lg * 4 + 3]);
    const f16x2 h26 = pk2(h_lds[48 + lg * 4], h_lds[48 + lg * 4 + 1]);
    const f16x2 h27 = pk2(h_lds[48 + lg * 4 + 2], h_lds[48 + lg * 4 + 3]);
    const f32x4 z4  = {0.f, 0.f, 0.f, 0.f};

    const int lgo = lg * 16;

    // ---------------- row-pair pipeline ----------------
    for (int rp = 0; rp < NRP; ++rp) {
        // issue NEXT row-pair's gathers into registers (no wait)
        float4 n0a, n0b, n1a, n1b;
        int    nf0 = 0, nd0 = 0, nf1 = 0, nd1 = 0;
        bool   nhas1 = false;
        if (rp + 1 < NRP) {
            const int off = (rp + 1) * 2 * NUM_F;
            nf0 = t >> 3; nd0 = t & 7;
            n0a = emb4[(size_t)s_idx[off + nf0] * 16 + nd0 * 2];
            n0b = emb4[(size_t)s_idx[off + nf0] * 16 + nd0 * 2 + 1];
            const int i1 = t + 512;
            nhas1 = i1 < NITEMS;
            nf1 = i1 >> 3; nd1 = i1 & 7;
            if (nhas1) {
                n1a = emb4[(size_t)s_idx[off + nf1] * 16 + nd1 * 2];
                n1b = emb4[(size_t)s_idx[off + nf1] * 16 + nd1 * 2 + 1];
            }
        }

        const char* e_base = (const char*)&e_lds[rp & 1][row][0][0];

        // -------- compute loop: table + e-row software pipeline (depth 1) --------
        unsigned rc_nxt = pairOff[((wv + 4) << 4) + la];
        f16x8 er0, er1, ec0, ec1;
        {
            const unsigned rc = pairOff[(wv << 4) + la];
            const unsigned ro = rc & 0xFFFFu;
            const unsigned co = rc >> 16;
            er0 = *(const f16x8*)(e_base + ro + lgo);
            er1 = *(const f16x8*)(e_base + ro + lgo + 64);
            ec0 = *(const f16x8*)(e_base + co + lgo);
            ec1 = *(const f16x8*)(e_base + co + lgo + 64);
        }
        #pragma unroll 1
        for (int it = 0; it < 12; ++it) {
            const int tile = wv + it * 4;          // < 48
            const int p    = (tile << 4) + la;

            // consume current e-rows
            const f16x8 B0 = er0 * ec0;            // v_pk_mul_f16
            const f16x8 B1 = er1 * ec1;

            // issue next iteration's e-reads now (addr from pipelined table)
            if (it < 11) {
                const unsigned rc = rc_nxt;
                if (it < 10) rc_nxt = pairOff[((wv + (it + 2) * 4) << 4) + la];
                const unsigned ro = rc & 0xFFFFu;
                const unsigned co = rc >> 16;
                er0 = *(const f16x8*)(e_base + ro + lgo);
                er1 = *(const f16x8*)(e_base + ro + lgo + 64);
                ec0 = *(const f16x8*)(e_base + co + lgo);
                ec1 = *(const f16x8*)(e_base + co + lgo + 64);
            }

            __builtin_amdgcn_s_setprio(1);
            f32x4 a0 = __builtin_amdgcn_mfma_f32_16x16x32_f16(WA00, B0, b40, 0, 0, 0);
            f32x4 a1 = __builtin_amdgcn_mfma_f32_16x16x32_f16(WA10, B0, b41, 0, 0, 0);
            f32x4 a2 = __builtin_amdgcn_mfma_f32_16x16x32_f16(WA20, B0, b42, 0, 0, 0);
            f32x4 a3 = __builtin_amdgcn_mfma_f32_16x16x32_f16(WA30, B0, b43, 0, 0, 0);
            f32x4 aq = __builtin_amdgcn_mfma_f32_16x16x32_f16(PA0,  B0, z4,  0, 0, 0);
            a0 = __builtin_amdgcn_mfma_f32_16x16x32_f16(WA01, B1, a0, 0, 0, 0);
            a1 = __builtin_amdgcn_mfma_f32_16x16x32_f16(WA11, B1, a1, 0, 0, 0);
            a2 = __builtin_amdgcn_mfma_f32_16x16x32_f16(WA21, B1, a2, 0, 0, 0);
            a3 = __builtin_amdgcn_mfma_f32_16x16x32_f16(WA31, B1, a3, 0, 0, 0);
            aq = __builtin_amdgcn_mfma_f32_16x16x32_f16(PA1,  B1, aq, 0, 0, 0);
            __builtin_amdgcn_s_setprio(0);

            // packed-f16 epilogue: 8 pkrtz + 8 relu2 + 8 pk mul/fma + 3 adds
            f16x2 fa = relu2(pk2(a0[0], a0[1])) * h20;
            f16x2 fb = relu2(pk2(a0[2], a0[3])) * h21;
            fa = relu2(pk2(a1[0], a1[1])) * h22 + fa;
            fb = relu2(pk2(a1[2], a1[3])) * h23 + fb;
            fa = relu2(pk2(a2[0], a2[1])) * h24 + fa;
            fb = relu2(pk2(a2[2], a2[3])) * h25 + fb;
            fa = relu2(pk2(a3[0], a3[1])) * h26 + fa;
            fb = relu2(pk2(a3[2], a3[3])) * h27 + fb;
            const f16x2 fs = fa + fb;

            // per-lg partial store (padded planes -> staggered banks)
            tsp[row][lg][p] = (float)fs[0] + (float)fs[1];
            if (lg == 0) q_s[row][p] = aq[0];   // exact: q lives at C row 0
        }
        __syncthreads();

        // -------- per-row softmax + pooling (lg-partials summed here) --------
        const int t2 = wv * 64 + lane;
        float sv0, sv1, sv2, qv0, qv1, qv2;
        {
            sv0 = (tsp[row][0][t2] + tsp[row][1][t2])
                + (tsp[row][2][t2] + tsp[row][3][t2]);
            qv0 = q_s[row][t2];
            sv1 = (tsp[row][0][t2 + 256] + tsp[row][1][t2 + 256])
                + (tsp[row][2][t2 + 256] + tsp[row][3][t2 + 256]);
            qv1 = q_s[row][t2 + 256];
            const bool ok2 = (t2 + 512) < NUM_P;
            sv2 = ok2 ? ((tsp[row][0][t2 + 512] + tsp[row][1][t2 + 512])
                       + (tsp[row][2][t2 + 512] + tsp[row][3][t2 + 512])) : -1e30f;
            qv2 = ok2 ? q_s[row][t2 + 512] : 0.f;
            if (t2 + 256 >= NUM_P) { sv1 = -1e30f; qv1 = 0.f; }
            if (t2 >= NUM_P)       { sv0 = -1e30f; qv0 = 0.f; }
        }

        float m3 = fmaxf(fmaxf(sv0, sv1), sv2);
        #pragma unroll
        for (int mm = 1; mm < 64; mm <<= 1) m3 = fmaxf(m3, __shfl_xor(m3, mm));
        if (lane == 0) wredM[wave] = m3;
        __syncthreads();
        const int r4 = row * 4;
        const float M = fmaxf(fmaxf(wredM[r4 + 0], wredM[r4 + 1]),
                              fmaxf(wredM[r4 + 2], wredM[r4 + 3]));

        float e0 = __expf(sv0 - M);
        float e1 = __expf(sv1 - M);
        float e2 = __expf(sv2 - M);
        float S  = e0 + e1 + e2;
        float Q  = fmaf(e0, qv0, fmaf(e1, qv1, e2 * qv2));
        #pragma unroll
        for (int mm = 1; mm < 64; mm <<= 1) {
            S += __shfl_xor(S, mm);
            Q += __shfl_xor(Q, mm);
        }
        if (lane == 0) { wredS[wave] = S; wredQ[wave] = Q; }
        __syncthreads();

        if (lane == 0 && wv == 0) {
            const float Ssum = wredS[r4] + wredS[r4 + 1] + wredS[r4 + 2] + wredS[r4 + 3];
            const float Qsum = wredQ[r4] + wredQ[r4 + 1] + wredQ[r4 + 2] + wredQ[r4 + 3];
            const float att_pool = Qsum / Ssum;
            const float x = bias[0] + s_yfirst[rp * 2 + row] + att_pool;
            out[blk * (2 * NRP) + rp * 2 + row] = 1.f / (1.f + __expf(-x));
        }

        // -------- write prefetched E into the other buffer --------
        if (rp + 1 < NRP) {
            const int off = (rp + 1) * 2 * NUM_F;
            {
                int rr = (nf0 >= NUM_F), ff = nf0 - rr * NUM_F;
                *(f16x8*)&e_lds[(rp + 1) & 1][rr][ff][nd0 * 8] =
                    pack8(n0a, n0b, s_fv[off + nf0]);
            }
            if (nhas1) {
                int rr = (nf1 >= NUM_F), ff = nf1 - rr * NUM_F;
                *(f16x8*)&e_lds[(rp + 1) & 1][rr][ff][nd1 * 8] =
                    pack8(n1a, n1b, s_fv[off + nf1]);
            }
            __syncthreads();
        }
    }
}

extern "C" void kernel_launch(void* const* d_in, const int* in_sizes, int n_in,
                              void* d_out, int out_size, void* d_ws, size_t ws_size,
                              hipStream_t stream) {
    const int*   feat_index = (const int*)  d_in[0];
    const float* feat_value = (const float*)d_in[1];
    const float* fo_w       = (const float*)d_in[2];
    const float* emb_table  = (const float*)d_in[3];
    const float* att_W      = (const float*)d_in[4];
    const float* att_b      = (const float*)d_in[5];
    const float* att_h      = (const float*)d_in[6];
    const float* p_vec      = (const float*)d_in[7];
    const float* bias       = (const float*)d_in[8];
    float*       out        = (float*)d_out;

    const int B = in_sizes[0] / NUM_F;   // 2048

    afm_epf<<<B / (2 * NRP), 512, 0, stream>>>(feat_index, feat_value, fo_w, emb_table,
                                               att_W, att_b, att_h, p_vec, bias, out);
}

// Round 23
// 25.112 us; speedup vs baseline: 1.3105x; 1.3105x over previous
//
#include <hip/hip_runtime.h>
#include <hip/hip_fp16.h>

#define NUM_F  39
#define NUM_P  741      // 39*38/2
#define NPAD   768      // 48 tiles * 16
#define NPP    (NPAD + 8)   // padded lg-plane stride (3104 B: +8 banks per lg)
#define DIM    64
#define ESTRH  72       // fp16 row stride in halves; 144 B rows (16B aligned)
#define NRP    2        // row-pairs per block (4 batch rows)
#define NITEMS (2 * NUM_F * 8)   // 624 gather items per row-pair

typedef float    f32x4 __attribute__((ext_vector_type(4)));
typedef _Float16 f16x8 __attribute__((ext_vector_type(8)));
typedef _Float16 f16x2 __attribute__((ext_vector_type(2)));
typedef __fp16   h16x2 __attribute__((ext_vector_type(2)));

static __device__ __forceinline__ f16x8 pack8(float4 v0, float4 v1, float fv) {
    f16x8 hv;
    hv[0] = (_Float16)(v0.x * fv);
    hv[1] = (_Float16)(v0.y * fv);
    hv[2] = (_Float16)(v0.z * fv);
    hv[3] = (_Float16)(v0.w * fv);
    hv[4] = (_Float16)(v1.x * fv);
    hv[5] = (_Float16)(v1.y * fv);
    hv[6] = (_Float16)(v1.z * fv);
    hv[7] = (_Float16)(v1.w * fv);
    return hv;
}

static __device__ __forceinline__ f16x2 pk2(float a, float b) {
    union { h16x2 p; f16x2 v; } u;
    u.p = __builtin_amdgcn_cvt_pkrtz(a, b);
    return u.v;
}
static __device__ __forceinline__ f16x2 relu2(f16x2 x) {
#if __has_builtin(__builtin_elementwise_max)
    const f16x2 z = {(_Float16)0.f, (_Float16)0.f};
    return __builtin_elementwise_max(x, z);
#else
    f16x2 r;
    r[0] = (x[0] > (_Float16)0.f) ? x[0] : (_Float16)0.f;
    r[1] = (x[1] > (_Float16)0.f) ? x[1] : (_Float16)0.f;
    return r;
#endif
}

__global__ __launch_bounds__(512, 2) void afm_plg2(
    const int*   __restrict__ feat_index,   // [B, F]
    const float* __restrict__ feat_value,   // [B, F]
    const float* __restrict__ fo_w,         // [NUM_FEATS, 1]
    const float* __restrict__ emb_table,    // [NUM_FEATS, 64]
    const float* __restrict__ att_W,        // [64, 64] (d, a)
    const float* __restrict__ att_b,        // [64]
    const float* __restrict__ att_h,        // [64]
    const float* __restrict__ p_vec,        // [64]
    const float* __restrict__ bias,         // [1]
    float*       __restrict__ out)          // [B]
{
    const int blk  = blockIdx.x;            // batch rows 4*blk .. 4*blk+3
    const int t    = threadIdx.x;
    const int wave = t >> 6;                // 0..7
    const int lane = t & 63;
    const int row  = wave >> 2;             // 0 or 1 (within row-pair)
    const int wv   = wave & 3;              // wave-within-row
    const int la   = lane & 15;             // pair-within-tile (B/C col)
    const int lg   = lane >> 4;             // k-group / C row-group

    __shared__ __half       e_lds[2][2][NUM_F][ESTRH]; // [buf][row] (22.5 KB)
    __shared__ __half       Wt[DIM][ESTRH];            // W^T fp16 (9 KB)
    __shared__ float        tsp[2][4][NPP];            // per-lg ts partials (24.8 KB, padded)
    __shared__ float        q_s[2][NPAD];              // q per pair (6.1 KB)
    __shared__ float        b_lds[DIM], h_lds[DIM], pv_lds[DIM];
    __shared__ unsigned int pairOff[NPAD];             // r*144 | (c*144<<16)
    __shared__ int          s_idx[2 * NRP * NUM_F];
    __shared__ float        s_fv[2 * NRP * NUM_F];
    __shared__ float        yf_s[2 * NRP * NUM_F];
    __shared__ float        s_yfirst[2 * NRP];
    __shared__ float        wredM[8], wredS[8], wredQ[8];

    const float4* emb4 = (const float4*)emb_table;

    // ---------------- A1: idx/fv/yf for all 4 rows + W + tables ----------------
    if (t < 2 * NRP * NUM_F) {
        int   idx = feat_index[blk * 2 * NRP * NUM_F + t];
        float fv  = feat_value[blk * 2 * NRP * NUM_F + t];
        s_idx[t]  = idx;
        s_fv[t]   = fv;
        yf_s[t]   = fo_w[idx] * fv;
    }
    if (t < DIM) {
        b_lds[t]  = att_b[t];
        h_lds[t]  = att_h[t];
        pv_lds[t] = p_vec[t];
    }
    if (t >= 192 && t < 192 + NUM_F) {   // pair table
        int r = t - 192, off = r * (2 * NUM_F - r - 1) / 2;
        const unsigned int rb = (unsigned int)(r * (ESTRH * 2));
        for (int c = r + 1; c < NUM_F; ++c) {
            pairOff[off] = rb | ((unsigned int)(c * (ESTRH * 2)) << 16);
            ++off;
        }
    }
    if (t >= 256 && t < 256 + (NPAD - NUM_P)) pairOff[NUM_P + (t - 256)] = 0;
    for (int q = t; q < DIM * DIM; q += 512) {       // W^T -> fp16 LDS
        int d = q >> 6, a = q & 63;
        Wt[a][d] = (__half)(_Float16)att_W[q];
    }
    __syncthreads();

    // y_first: waves 0..3 each reduce one of the 4 rows
    if (wave < 2 * NRP) {
        float yf = (lane < NUM_F) ? yf_s[wave * NUM_F + lane] : 0.f;
        #pragma unroll
        for (int m = 1; m < 64; m <<= 1) yf += __shfl_xor(yf, m);
        if (lane == 0) s_yfirst[wave] = yf;
    }

    // ---------------- A2: stage E for rp=0 (serial, once) ----------------
    {
        const int f0 = t >> 3, d80 = t & 7;          // item t (always < 624)
        float4 v0a = emb4[(size_t)s_idx[f0] * 16 + d80 * 2];
        float4 v0b = emb4[(size_t)s_idx[f0] * 16 + d80 * 2 + 1];
        const int  i1   = t + 512;
        const bool has1 = i1 < NITEMS;
        const int  f1 = i1 >> 3, d81 = i1 & 7;
        float4 v1a, v1b;
        if (has1) {
            v1a = emb4[(size_t)s_idx[f1] * 16 + d81 * 2];
            v1b = emb4[(size_t)s_idx[f1] * 16 + d81 * 2 + 1];
        }
        {
            int rr = (f0 >= NUM_F), ff = f0 - rr * NUM_F;
            *(f16x8*)&e_lds[0][rr][ff][d80 * 8] = pack8(v0a, v0b, s_fv[f0]);
        }
        if (has1) {
            int rr = (f1 >= NUM_F), ff = f1 - rr * NUM_F;
            *(f16x8*)&e_lds[0][rr][ff][d81 * 8] = pack8(v1a, v1b, s_fv[f1]);
        }
    }
    __syncthreads();

    // ---------------- stationary fragments (named SSA, hoisted) ----------------
    const f16x8 WA00 = *(const f16x8*)&Wt[ 0 + la][ 0 + lg * 8];
    const f16x8 WA01 = *(const f16x8*)&Wt[ 0 + la][32 + lg * 8];
    const f16x8 WA10 = *(const f16x8*)&Wt[16 + la][ 0 + lg * 8];
    const f16x8 WA11 = *(const f16x8*)&Wt[16 + la][32 + lg * 8];
    const f16x8 WA20 = *(const f16x8*)&Wt[32 + la][ 0 + lg * 8];
    const f16x8 WA21 = *(const f16x8*)&Wt[32 + la][32 + lg * 8];
    const f16x8 WA30 = *(const f16x8*)&Wt[48 + la][ 0 + lg * 8];
    const f16x8 WA31 = *(const f16x8*)&Wt[48 + la][32 + lg * 8];

    f16x8 PA0 = (f16x8)(_Float16)0.f;
    f16x8 PA1 = (f16x8)(_Float16)0.f;
    if (la == 0) {
        #pragma unroll
        for (int j = 0; j < 8; ++j) {
            PA0[j] = (_Float16)pv_lds[     lg * 8 + j];
            PA1[j] = (_Float16)pv_lds[32 + lg * 8 + j];
        }
    }

    const f32x4 b40 = *(const f32x4*)&b_lds[ 0 + lg * 4];
    const f32x4 b41 = *(const f32x4*)&b_lds[16 + lg * 4];
    const f32x4 b42 = *(const f32x4*)&b_lds[32 + lg * 4];
    const f32x4 b43 = *(const f32x4*)&b_lds[48 + lg * 4];
    // h as packed f16 pairs for the packed epilogue
    const f16x2 h20 = pk2(h_lds[ 0 + lg * 4], h_lds[ 0 + lg * 4 + 1]);
    const f16x2 h21 = pk2(h_lds[ 0 + lg * 4 + 2], h_lds[ 0 + lg * 4 + 3]);
    const f16x2 h22 = pk2(h_lds[16 + lg * 4], h_lds[16 + lg * 4 + 1]);
    const f16x2 h23 = pk2(h_lds[16 + lg * 4 + 2], h_lds[16 + lg * 4 + 3]);
    const f16x2 h24 = pk2(h_lds[32 + lg * 4], h_lds[32 + lg * 4 + 1]);
    const f16x2 h25 = pk2(h_lds[32 + lg * 4 + 2], h_lds[32 + lg * 4 + 3]);
    const f16x2 h26 = pk2(h_lds[48 + lg * 4], h_lds[48 + lg * 4 + 1]);
    const f16x2 h27 = pk2(h_lds[48 + lg * 4 + 2], h_lds[48 + lg * 4 + 3]);
    const f32x4 z4  = {0.f, 0.f, 0.f, 0.f};

    const int lgo = lg * 16;

    // ---------------- row-pair pipeline ----------------
    for (int rp = 0; rp < NRP; ++rp) {
        // issue NEXT row-pair's gathers into registers (no wait)
        float4 n0a, n0b, n1a, n1b;
        int    nf0 = 0, nd0 = 0, nf1 = 0, nd1 = 0;
        bool   nhas1 = false;
        if (rp + 1 < NRP) {
            const int off = (rp + 1) * 2 * NUM_F;
            nf0 = t >> 3; nd0 = t & 7;
            n0a = emb4[(size_t)s_idx[off + nf0] * 16 + nd0 * 2];
            n0b = emb4[(size_t)s_idx[off + nf0] * 16 + nd0 * 2 + 1];
            const int i1 = t + 512;
            nhas1 = i1 < NITEMS;
            nf1 = i1 >> 3; nd1 = i1 & 7;
            if (nhas1) {
                n1a = emb4[(size_t)s_idx[off + nf1] * 16 + nd1 * 2];
                n1b = emb4[(size_t)s_idx[off + nf1] * 16 + nd1 * 2 + 1];
            }
        }

        const char* e_base = (const char*)&e_lds[rp & 1][row][0][0];

        // -------- compute loop: table software-pipelined (depth 1), no shfl --------
        unsigned rc_cur = pairOff[(wv << 4) + la];
        #pragma unroll 1
        for (int it = 0; it < 12; ++it) {
            const int tile = wv + it * 4;          // < 48
            const int p    = (tile << 4) + la;
            const unsigned rc = rc_cur;
            // issue next iteration's table read now; overlaps MFMA/epilogue below
            if (it < 11) rc_cur = pairOff[((wv + (it + 1) * 4) << 4) + la];
            const unsigned ro = rc & 0xFFFFu;
            const unsigned co = rc >> 16;

            const f16x8 er0 = *(const f16x8*)(e_base + ro + lgo);
            const f16x8 er1 = *(const f16x8*)(e_base + ro + lgo + 64);
            const f16x8 ec0 = *(const f16x8*)(e_base + co + lgo);
            const f16x8 ec1 = *(const f16x8*)(e_base + co + lgo + 64);
            const f16x8 B0 = er0 * ec0;            // v_pk_mul_f16
            const f16x8 B1 = er1 * ec1;

            __builtin_amdgcn_s_setprio(1);
            f32x4 a0 = __builtin_amdgcn_mfma_f32_16x16x32_f16(WA00, B0, b40, 0, 0, 0);
            f32x4 a1 = __builtin_amdgcn_mfma_f32_16x16x32_f16(WA10, B0, b41, 0, 0, 0);
            f32x4 a2 = __builtin_amdgcn_mfma_f32_16x16x32_f16(WA20, B0, b42, 0, 0, 0);
            f32x4 a3 = __builtin_amdgcn_mfma_f32_16x16x32_f16(WA30, B0, b43, 0, 0, 0);
            f32x4 aq = __builtin_amdgcn_mfma_f32_16x16x32_f16(PA0,  B0, z4,  0, 0, 0);
            a0 = __builtin_amdgcn_mfma_f32_16x16x32_f16(WA01, B1, a0, 0, 0, 0);
            a1 = __builtin_amdgcn_mfma_f32_16x16x32_f16(WA11, B1, a1, 0, 0, 0);
            a2 = __builtin_amdgcn_mfma_f32_16x16x32_f16(WA21, B1, a2, 0, 0, 0);
            a3 = __builtin_amdgcn_mfma_f32_16x16x32_f16(WA31, B1, a3, 0, 0, 0);
            aq = __builtin_amdgcn_mfma_f32_16x16x32_f16(PA1,  B1, aq, 0, 0, 0);
            __builtin_amdgcn_s_setprio(0);

            // packed-f16 epilogue: 8 pkrtz + 8 relu2 + 8 pk mul/fma + 3 adds
            f16x2 fa = relu2(pk2(a0[0], a0[1])) * h20;
            f16x2 fb = relu2(pk2(a0[2], a0[3])) * h21;
            fa = relu2(pk2(a1[0], a1[1])) * h22 + fa;
            fb = relu2(pk2(a1[2], a1[3])) * h23 + fb;
            fa = relu2(pk2(a2[0], a2[1])) * h24 + fa;
            fb = relu2(pk2(a2[2], a2[3])) * h25 + fb;
            fa = relu2(pk2(a3[0], a3[1])) * h26 + fa;
            fb = relu2(pk2(a3[2], a3[3])) * h27 + fb;
            const f16x2 fs = fa + fb;

            // per-lg partial store (padded planes -> staggered banks)
            tsp[row][lg][p] = (float)fs[0] + (float)fs[1];
            if (lg == 0) q_s[row][p] = aq[0];   // exact: q lives at C row 0
        }
        __syncthreads();

        // -------- per-row softmax + pooling (lg-partials summed here) --------
        const int t2 = wv * 64 + lane;
        float sv0, sv1, sv2, qv0, qv1, qv2;
        {
            sv0 = (tsp[row][0][t2] + tsp[row][1][t2])
                + (tsp[row][2][t2] + tsp[row][3][t2]);
            qv0 = q_s[row][t2];
            sv1 = (tsp[row][0][t2 + 256] + tsp[row][1][t2 + 256])
                + (tsp[row][2][t2 + 256] + tsp[row][3][t2 + 256]);
            qv1 = q_s[row][t2 + 256];
            const bool ok2 = (t2 + 512) < NUM_P;
            sv2 = ok2 ? ((tsp[row][0][t2 + 512] + tsp[row][1][t2 + 512])
                       + (tsp[row][2][t2 + 512] + tsp[row][3][t2 + 512])) : -1e30f;
            qv2 = ok2 ? q_s[row][t2 + 512] : 0.f;
            if (t2 + 256 >= NUM_P) { sv1 = -1e30f; qv1 = 0.f; }
            if (t2 >= NUM_P)       { sv0 = -1e30f; qv0 = 0.f; }
        }

        float m3 = fmaxf(fmaxf(sv0, sv1), sv2);
        #pragma unroll
        for (int mm = 1; mm < 64; mm <<= 1) m3 = fmaxf(m3, __shfl_xor(m3, mm));
        if (lane == 0) wredM[wave] = m3;
        __syncthreads();
        const int r4 = row * 4;
        const float M = fmaxf(fmaxf(wredM[r4 + 0], wredM[r4 + 1]),
                              fmaxf(wredM[r4 + 2], wredM[r4 + 3]));

        float e0 = __expf(sv0 - M);
        float e1 = __expf(sv1 - M);
        float e2 = __expf(sv2 - M);
        float S  = e0 + e1 + e2;
        float Q  = fmaf(e0, qv0, fmaf(e1, qv1, e2 * qv2));
        #pragma unroll
        for (int mm = 1; mm < 64; mm <<= 1) {
            S += __shfl_xor(S, mm);
            Q += __shfl_xor(Q, mm);
        }
        if (lane == 0) { wredS[wave] = S; wredQ[wave] = Q; }
        __syncthreads();

        if (lane == 0 && wv == 0) {
            const float Ssum = wredS[r4] + wredS[r4 + 1] + wredS[r4 + 2] + wredS[r4 + 3];
            const float Qsum = wredQ[r4] + wredQ[r4 + 1] + wredQ[r4 + 2] + wredQ[r4 + 3];
            const float att_pool = Qsum / Ssum;
            const float x = bias[0] + s_yfirst[rp * 2 + row] + att_pool;
            out[blk * (2 * NRP) + rp * 2 + row] = 1.f / (1.f + __expf(-x));
        }

        // -------- write prefetched E into the other buffer --------
        if (rp + 1 < NRP) {
            const int off = (rp + 1) * 2 * NUM_F;
            {
                int rr = (nf0 >= NUM_F), ff = nf0 - rr * NUM_F;
                *(f16x8*)&e_lds[(rp + 1) & 1][rr][ff][nd0 * 8] =
                    pack8(n0a, n0b, s_fv[off + nf0]);
            }
            if (nhas1) {
                int rr = (nf1 >= NUM_F), ff = nf1 - rr * NUM_F;
                *(f16x8*)&e_lds[(rp + 1) & 1][rr][ff][nd1 * 8] =
                    pack8(n1a, n1b, s_fv[off + nf1]);
            }
            __syncthreads();
        }
    }
}

extern "C" void kernel_launch(void* const* d_in, const int* in_sizes, int n_in,
                              void* d_out, int out_size, void* d_ws, size_t ws_size,
                              hipStream_t stream) {
    const int*   feat_index = (const int*)  d_in[0];
    const float* feat_value = (const float*)d_in[1];
    const float* fo_w       = (const float*)d_in[2];
    const float* emb_table  = (const float*)d_in[3];
    const float* att_W      = (const float*)d_in[4];
    const float* att_b      = (const float*)d_in[5];
    const float* att_h      = (const float*)d_in[6];
    const float* p_vec      = (const float*)d_in[7];
    const float* bias       = (const float*)d_in[8];
    float*       out        = (float*)d_out;

    const int B = in_sizes[0] / NUM_F;   // 2048

    afm_plg2<<<B / (2 * NRP), 512, 0, stream>>>(feat_index, feat_value, fo_w, emb_table,
                                                att_W, att_b, att_h, p_vec, bias, out);
}